// Round 10
// baseline (1541.996 us; speedup 1.0000x reference)
//
#include <hip/hip_runtime.h>

#define T_STEPS 256
#define BATCH   256
#define DIN     1024
#define DH      1024

typedef _Float16 half8_t __attribute__((ext_vector_type(8)));
typedef _Float16 half4_t __attribute__((ext_vector_type(4)));
typedef float    f32x4_t __attribute__((ext_vector_type(4)));

#define LDH  1032   // padded LDS row stride (halves) for h slab (rnn)
#define REDW 68     // padded row stride (floats) for epilogue transpose (rnn)
#define LGW  72     // padded LDS row stride (halves) for zgemm tiles (+8 pad)

// aux/cpol bits on gfx950: bit0 = sc0, bit4 = sc1 -> 17 = system-scope bypass
#define CPOL_SYS 17

union H4U { half4_t h; unsigned long long u; };

// Fast tanh: 1 - 2/(exp2(2*log2e*x)+1); error ~1e-7 << fp16 h quantization.
__device__ __forceinline__ float ftanh(float x) {
    float t = x * 2.885390081777927f;   // 2*log2(e)
    float e = exp2f(t);
    float r = __builtin_amdgcn_rcpf(e + 1.0f);
    return 1.0f - 2.0f * r;
}

// ---------------------------------------------------------------------------
// Split W (1024 x 2048 fp32) into Wh = W[:, :1024] and Wx = W[:, 1024:], fp16.
// ---------------------------------------------------------------------------
__global__ __launch_bounds__(256) void cvt_w(const float* __restrict__ W,
                                             _Float16* __restrict__ Wh,
                                             _Float16* __restrict__ Wx) {
    const int part = blockIdx.x >> 9;                         // 0: Wh, 1: Wx
    size_t base = ((size_t)(blockIdx.x & 511) * 256 + threadIdx.x) * 8;
    const int n = (int)(base >> 10);
    const int k = (int)(base & 1023);
    const float4* s = reinterpret_cast<const float4*>(W + (size_t)n * 2048 + part * 1024 + k);
    float4 a = s[0], b = s[1];
    half8_t h;
    h[0] = (_Float16)a.x; h[1] = (_Float16)a.y;
    h[2] = (_Float16)a.z; h[3] = (_Float16)a.w;
    h[4] = (_Float16)b.x; h[5] = (_Float16)b.y;
    h[6] = (_Float16)b.z; h[7] = (_Float16)b.w;
    _Float16* dst = part ? Wx : Wh;
    *reinterpret_cast<half8_t*>(dst + base) = h;
}

// ---------------------------------------------------------------------------
// out[0] = zeros; block 0 zeroes the 256 sync flags (16-int stride) with
// system-scope stores. (R4/R6-proven)
// ---------------------------------------------------------------------------
__global__ __launch_bounds__(256) void zero_h0(float* __restrict__ out,
                                               int* __restrict__ flags) {
    size_t i = (size_t)blockIdx.x * 256 + threadIdx.x;
    reinterpret_cast<float4*>(out)[i] = make_float4(0.f, 0.f, 0.f, 0.f);
    if (blockIdx.x == 0) {
#pragma unroll
        for (int j = 0; j < 16; ++j)
            __hip_atomic_store(&flags[(int)threadIdx.x * 16 + j], 0,
                               __ATOMIC_RELAXED, __HIP_MEMORY_SCOPE_SYSTEM);
    }
}

// ---------------------------------------------------------------------------
// Z = seq @ Wx^T + bias into out[1..256].  M=65536, N=1024, K=1024.
// m93-shape: 128x128 tile, BK=64, 16 iters, 256 thr = 4 waves (2x2), each
// wave 64x64 = 4x4 accs of 16x16x32 f16 MFMA (32 MFMAs/wave/iter; 2x the
// per-barrier work of the R4 64x64 version). Both A (fp32->fp16 cvt) and B
// (fp16) reg-staged + ds_write_b128 into 72-half-padded rows (+8 pad = 4-bank
// row rotation -> breaks the 16-way b128 read conflict). LDS 36 KB -> 4
// WGs/CU. Index algebra is the direct mi/ni in 0..3 generalization of the
// R4-PROVEN 2x2 pattern (no swizzle anywhere).
// Grid: flat 4096, R6-proven bijective XCD remap: nblk=(id>>3)&7,
// mblk=(id&7)+8*(id>>6) -> the 8 nblk-WGs of an m-stripe share id%8 -> one
// XCD; A-stripe fetched into exactly one L2.
// ---------------------------------------------------------------------------
__global__ __launch_bounds__(256) void zgemm(const float* __restrict__ seq,
                                             const _Float16* __restrict__ Wx,
                                             const float* __restrict__ bias,
                                             float* __restrict__ out) {
    __shared__ __align__(16) _Float16 la[128 * LGW];
    __shared__ __align__(16) _Float16 lb[128 * LGW];

    const int tid  = threadIdx.x;
    const int id   = blockIdx.x;               // 0..4095
    const int nblk = (id >> 3) & 7;            // 0..7
    const int mblk = (id & 7) + 8 * (id >> 6); // 0..511
    const int m0 = mblk * 128;
    const int n0 = nblk * 128;

    const float* __restrict__ X = seq + (size_t)m0 * 1024;
    float* __restrict__ Z = out + (size_t)BATCH * DH + (size_t)m0 * 1024 + n0;

    // Staging map: row ar = tid>>1 (0..127), k-half kh = tid&1 (32 elems).
    const int ar = tid >> 1;
    const int kh = tid & 1;
    const float*    Asrc = X  + (size_t)ar * 1024 + kh * 32;
    const _Float16* Bsrc = Wx + (size_t)(n0 + ar) * 1024 + kh * 32;

    float4 af[8];
    uint4  bq[4];
    auto load_tiles = [&](int kb) {
        const float4* s4 = reinterpret_cast<const float4*>(Asrc + kb);
#pragma unroll
        for (int i = 0; i < 8; ++i) af[i] = s4[i];
        const uint4* sb = reinterpret_cast<const uint4*>(Bsrc + kb);
#pragma unroll
        for (int i = 0; i < 4; ++i) bq[i] = sb[i];
    };
    auto store_tiles = [&]() {
#pragma unroll
        for (int j = 0; j < 4; ++j) {
            half8_t h;
            h[0] = (_Float16)af[2 * j].x;     h[1] = (_Float16)af[2 * j].y;
            h[2] = (_Float16)af[2 * j].z;     h[3] = (_Float16)af[2 * j].w;
            h[4] = (_Float16)af[2 * j + 1].x; h[5] = (_Float16)af[2 * j + 1].y;
            h[6] = (_Float16)af[2 * j + 1].z; h[7] = (_Float16)af[2 * j + 1].w;
            *reinterpret_cast<half8_t*>(&la[ar * LGW + kh * 32 + j * 8]) = h;
        }
#pragma unroll
        for (int i = 0; i < 4; ++i)
            *reinterpret_cast<uint4*>(&lb[ar * LGW + kh * 32 + i * 8]) = bq[i];
    };

    const int wave = tid >> 6;
    const int lane = tid & 63;
    const int fr   = lane & 15;
    const int quad = lane >> 4;
    const int wm   = (wave >> 1) * 64;
    const int wn   = (wave & 1) * 64;

    f32x4_t acc[4][4];
#pragma unroll
    for (int i = 0; i < 4; ++i)
#pragma unroll
        for (int j = 0; j < 4; ++j) acc[i][j] = (f32x4_t){0.f, 0.f, 0.f, 0.f};

    load_tiles(0);
#pragma unroll 1
    for (int it = 0; it < 16; ++it) {
        store_tiles();
        __syncthreads();
        if (it < 15) load_tiles((it + 1) * 64);
#pragma unroll
        for (int kk = 0; kk < 2; ++kk) {
            const int ko = kk * 32 + quad * 8;
            half8_t a[4], b[4];
#pragma unroll
            for (int mi = 0; mi < 4; ++mi)
                a[mi] = *reinterpret_cast<const half8_t*>(
                    &la[(wm + mi * 16 + fr) * LGW + ko]);
#pragma unroll
            for (int ni = 0; ni < 4; ++ni)
                b[ni] = *reinterpret_cast<const half8_t*>(
                    &lb[(wn + ni * 16 + fr) * LGW + ko]);
#pragma unroll
            for (int mi = 0; mi < 4; ++mi)
#pragma unroll
                for (int ni = 0; ni < 4; ++ni)
                    acc[mi][ni] = __builtin_amdgcn_mfma_f32_16x16x32_f16(
                        a[mi], b[ni], acc[mi][ni], 0, 0, 0);
        }
        __syncthreads();
    }

    // Epilogue (R4-proven D layout): row = wm + mi*16 + quad*4 + q,
    // col = wn + ni*16 + fr.
#pragma unroll
    for (int ni = 0; ni < 4; ++ni) {
        const float bv = bias[n0 + wn + ni * 16 + fr];
#pragma unroll
        for (int mi = 0; mi < 4; ++mi) {
            const int mr = wm + mi * 16 + quad * 4;
#pragma unroll
            for (int q = 0; q < 4; ++q)
                Z[(size_t)(mr + q) * 1024 + wn + ni * 16 + fr] = acc[mi][ni][q] + bv;
        }
    }
}

// ---------------------------------------------------------------------------
// Persistent recurrence, cache-maintenance-free sync (byte-identical to the
// R4/R6-proven version, ~650 us / 2.55 us/step).
// ---------------------------------------------------------------------------
__global__ __launch_bounds__(256, 1) void rnn_persist(
        const _Float16* __restrict__ Wh,
        _Float16* __restrict__ Hh,
        int* __restrict__ flags,
        float* __restrict__ out) {
    __shared__ __align__(16) _Float16 hL[16 * LDH];
    __shared__ __align__(16) float redL[16 * REDW];

    const int tid  = threadIdx.x;
    const int m    = blockIdx.x & 15;
    const int n    = blockIdx.x >> 4;
    const int wave = tid >> 6;
    const int lane = tid & 63;
    const int fr   = lane & 15;
    const int quad = lane >> 4;

    // Wh fragments: wave's 16 cols x K=1024 -> 32 x half8 = 128 VGPRs.
    half8_t bfrag[32];
    {
        const _Float16* wp = Wh + (size_t)(n * 64 + wave * 16 + fr) * DH + quad * 8;
#pragma unroll
        for (int ks = 0; ks < 32; ++ks)
            bfrag[ks] = *reinterpret_cast<const half8_t*>(wp + ks * 32);
    }

    const int r  = tid >> 4;          // 0..15 batch row within tile
    const int c4 = (tid & 15) * 4;    // 0..60 col within tile
    const size_t orowg = (size_t)(m * 16 + r);
    int* myflag = flags + (m * 16 + n) * 16;

    // ---- t = 0: h1 = tanh(Z1) since h0 == 0 -> out[1] + Hh buffer 1 ----
    {
        float* o1 = out + ((size_t)BATCH + orowg) * DH + n * 64 + c4;
        float4 z = *reinterpret_cast<const float4*>(o1);
        float4 v = make_float4(ftanh(z.x), ftanh(z.y), ftanh(z.z), ftanh(z.w));
        *reinterpret_cast<float4*>(o1) = v;
        H4U cv;
        cv.h[0] = (_Float16)v.x; cv.h[1] = (_Float16)v.y;
        cv.h[2] = (_Float16)v.z; cv.h[3] = (_Float16)v.w;
        __hip_atomic_store(
            (unsigned long long*)(Hh + ((size_t)BATCH + orowg) * DH + n * 64 + c4),
            cv.u, __ATOMIC_RELAXED, __HIP_MEMORY_SCOPE_SYSTEM);
        __syncthreads();   // all write-through stores vmcnt-drained
        if (tid == 0)
            __hip_atomic_store(myflag, 1, __ATOMIC_RELAXED, __HIP_MEMORY_SCOPE_SYSTEM);
    }

    for (int s = 1; s < T_STEPS; ++s) {
        // Z prefetch (own tile of out[s+1]; written only by zgemm).
        float* o = out + ((size_t)(s + 1) * BATCH + orowg) * DH + n * 64 + c4;
        float4 z = *reinterpret_cast<const float4*>(o);

        // Wait for the 16 producers of group m to finish step s.
        if (tid < 16) {
            const int* f = flags + (m * 16 + tid) * 16;
            int guard = 0;
            while (__hip_atomic_load(f, __ATOMIC_RELAXED, __HIP_MEMORY_SCOPE_SYSTEM) < s) {
                if (++guard > (1 << 24)) break;   // bailout -> visible wrongness, not hang
            }
        }
        __syncthreads();

        // Stage h_s slab (16 x 1024 fp16 = 32 KB) into LDS, bypassing L1/L2.
        const _Float16* hsrc = Hh + ((size_t)(s & 1) * BATCH + (size_t)m * 16) * DH;
#pragma unroll
        for (int i = 0; i < 8; ++i) {
            const int c   = wave * 8 + i;    // 0..31 chunks of 1 KB
            const int row = c >> 1;
            const int hf  = c & 1;
            const _Float16* src = hsrc + (size_t)row * DH + hf * 512 + lane * 8;
            __builtin_amdgcn_global_load_lds(
                (const __attribute__((address_space(1))) void*)src,
                (__attribute__((address_space(3))) void*)&hL[row * LDH + hf * 512],
                16, 0, CPOL_SYS);
        }
        __syncthreads();

        // 32 MFMAs, two interleaved accumulator chains.
        f32x4_t acc0 = {0.f, 0.f, 0.f, 0.f}, acc1 = {0.f, 0.f, 0.f, 0.f};
        const _Float16* pa = &hL[fr * LDH + quad * 8];
#pragma unroll
        for (int ks = 0; ks < 16; ++ks) {
            half8_t ae = *reinterpret_cast<const half8_t*>(pa + (2 * ks) * 32);
            half8_t ao = *reinterpret_cast<const half8_t*>(pa + (2 * ks + 1) * 32);
            acc0 = __builtin_amdgcn_mfma_f32_16x16x32_f16(ae, bfrag[2 * ks],     acc0, 0, 0, 0);
            acc1 = __builtin_amdgcn_mfma_f32_16x16x32_f16(ao, bfrag[2 * ks + 1], acc1, 0, 0, 0);
        }
        f32x4_t sum = acc0 + acc1;

        // Transpose D-layout (row=quad*4+q batch, col=wave*16+fr) via LDS.
#pragma unroll
        for (int q = 0; q < 4; ++q)
            redL[(quad * 4 + q) * REDW + wave * 16 + fr] = sum[q];
        __syncthreads();

        f32x4_t t4 = *reinterpret_cast<const f32x4_t*>(&redL[r * REDW + c4]);
        float4 v = make_float4(ftanh(t4[0] + z.x), ftanh(t4[1] + z.y),
                               ftanh(t4[2] + z.z), ftanh(t4[3] + z.w));
        *reinterpret_cast<float4*>(o) = v;
        H4U cv;
        cv.h[0] = (_Float16)v.x; cv.h[1] = (_Float16)v.y;
        cv.h[2] = (_Float16)v.z; cv.h[3] = (_Float16)v.w;
        __hip_atomic_store(
            (unsigned long long*)(Hh + ((size_t)((s + 1) & 1) * BATCH + orowg) * DH
                                  + n * 64 + c4),
            cv.u, __ATOMIC_RELAXED, __HIP_MEMORY_SCOPE_SYSTEM);

        __syncthreads();   // every thread's write-through stores drained
        if (tid == 0)
            __hip_atomic_store(myflag, s + 1, __ATOMIC_RELAXED, __HIP_MEMORY_SCOPE_SYSTEM);
    }
}

// ---------------------------------------------------------------------------
// Workspace layout (bytes):
//   [0, 2M)   Wh fp16 (1024 x 1024)
//   [2M, 4M)  Wx fp16 (1024 x 1024)
//   [4M, 5M)  Hh fp16 double buffer (2 x 256 x 1024)
//   [5M, +16K) flags int[256][16]
// ---------------------------------------------------------------------------
extern "C" void kernel_launch(void* const* d_in, const int* in_sizes, int n_in,
                              void* d_out, int out_size, void* d_ws, size_t ws_size,
                              hipStream_t stream) {
    const float* seq  = (const float*)d_in[0];   // (256, 256, 1024) fp32
    const float* W    = (const float*)d_in[1];   // (1024, 2048) fp32
    const float* bias = (const float*)d_in[2];   // (1024,) fp32
    float* out        = (float*)d_out;           // (257, 256, 1024) fp32
    _Float16* Wh      = (_Float16*)d_ws;
    _Float16* Wx      = (_Float16*)d_ws + 1024 * 1024;
    _Float16* Hh      = (_Float16*)d_ws + 2 * 1024 * 1024;
    int* flags        = (int*)((char*)d_ws + 5 * 1024 * 1024);

    hipLaunchKernelGGL(cvt_w, dim3(1024), dim3(256), 0, stream, W, Wh, Wx);
    hipLaunchKernelGGL(zero_h0, dim3(256), dim3(256), 0, stream, out, flags);
    hipLaunchKernelGGL(zgemm, dim3(4096), dim3(256), 0, stream, seq, Wx, bias, out);
    hipLaunchKernelGGL(rnn_persist, dim3(256), dim3(256), 0, stream, Wh, Hh, flags, out);
}

// Round 11
// 1332.611 us; speedup vs baseline: 1.1571x; 1.1571x over previous
//
#include <hip/hip_runtime.h>

#define T_STEPS 256
#define BATCH   256
#define DIN     1024
#define DH      1024

typedef _Float16 half8_t __attribute__((ext_vector_type(8)));
typedef _Float16 half4_t __attribute__((ext_vector_type(4)));
typedef float    f32x4_t __attribute__((ext_vector_type(4)));

#define LDH  1032   // padded LDS row stride (halves) for h slab (rnn role)
#define REDW 68     // padded row stride (floats) for epilogue transpose
#define LGW  72     // padded LDS row stride (halves) for zgemm tiles (+8 pad)
#define LDS_BYTES 37376   // max(rnn: 16*1032*2 + 16*68*4, zgemm: 2*128*72*2)

// aux/cpol bits on gfx950: bit0 = sc0, bit4 = sc1 -> 17 = system-scope bypass
#define CPOL_SYS 17

union H4U { half4_t h; unsigned long long u; };

// Fast tanh: 1 - 2/(exp2(2*log2e*x)+1); error ~1e-7 << fp16 h quantization.
__device__ __forceinline__ float ftanh(float x) {
    float t = x * 2.885390081777927f;   // 2*log2(e)
    float e = exp2f(t);
    float r = __builtin_amdgcn_rcpf(e + 1.0f);
    return 1.0f - 2.0f * r;
}

// ---------------------------------------------------------------------------
// Split W (1024 x 2048 fp32) into Wh = W[:, :1024] and Wx = W[:, 1024:], fp16.
// ---------------------------------------------------------------------------
__global__ __launch_bounds__(256) void cvt_w(const float* __restrict__ W,
                                             _Float16* __restrict__ Wh,
                                             _Float16* __restrict__ Wx) {
    const int part = blockIdx.x >> 9;                         // 0: Wh, 1: Wx
    size_t base = ((size_t)(blockIdx.x & 511) * 256 + threadIdx.x) * 8;
    const int n = (int)(base >> 10);
    const int k = (int)(base & 1023);
    const float4* s = reinterpret_cast<const float4*>(W + (size_t)n * 2048 + part * 1024 + k);
    float4 a = s[0], b = s[1];
    half8_t h;
    h[0] = (_Float16)a.x; h[1] = (_Float16)a.y;
    h[2] = (_Float16)a.z; h[3] = (_Float16)a.w;
    h[4] = (_Float16)b.x; h[5] = (_Float16)b.y;
    h[6] = (_Float16)b.z; h[7] = (_Float16)b.w;
    _Float16* dst = part ? Wx : Wh;
    *reinterpret_cast<half8_t*>(dst + base) = h;
}

// ---------------------------------------------------------------------------
// out[0] = zeros; block 0 zeroes the 256 sync flags (16-int stride), block 1
// zeroes the 4096 zrdy tile flags. All with system-scope stores.
// ---------------------------------------------------------------------------
__global__ __launch_bounds__(256) void zero_h0(float* __restrict__ out,
                                               int* __restrict__ flags,
                                               int* __restrict__ zrdy) {
    size_t i = (size_t)blockIdx.x * 256 + threadIdx.x;
    reinterpret_cast<float4*>(out)[i] = make_float4(0.f, 0.f, 0.f, 0.f);
    if (blockIdx.x == 0) {
#pragma unroll
        for (int j = 0; j < 16; ++j)
            __hip_atomic_store(&flags[(int)threadIdx.x * 16 + j], 0,
                               __ATOMIC_RELAXED, __HIP_MEMORY_SCOPE_SYSTEM);
    } else if (blockIdx.x == 1) {
#pragma unroll
        for (int j = 0; j < 16; ++j)
            __hip_atomic_store(&zrdy[(int)threadIdx.x * 16 + j], 0,
                               __ATOMIC_RELAXED, __HIP_MEMORY_SCOPE_SYSTEM);
    }
}

// ---------------------------------------------------------------------------
// MERGED pipeline: recurrence + input-GEMM in ONE dispatch, overlapped.
//  bids 0..255   : rnn role (dispatched FIRST -> co-resident, ~1/CU).
//  bids 256..4351: zgemm role (fill remaining ~3 slots/CU; R10-proven body).
// zgemm tile (mblk, nblk) writes Z = seq@Wx^T + bias into out[1..256] with
// SYSTEM write-through stores, drains via __syncthreads, then sets
// zrdy[mblk][nblk] (system-relaxed) -- the same publish protocol proven for
// Hh/flags since R4. rnn WG (m,n) at step s needs exactly tile
// (2s + (m>>3), n>>1); it polls that flag alongside its 16 peer h-flags,
// then reads Z with system-bypass loads (IF$ authoritative).
// rnn body otherwise byte-equivalent to the R4/R10-proven rnn_persist.
// All polls carry bailout guards: a broken scheduling assumption produces
// visible wrongness, never a hang.
// ---------------------------------------------------------------------------
__global__ __launch_bounds__(256, 1) void fused_pipeline(
        const _Float16* __restrict__ Wh,
        const _Float16* __restrict__ Wx,
        const float* __restrict__ bias,
        const float* __restrict__ seq,
        _Float16* __restrict__ Hh,
        int* __restrict__ flags,
        int* __restrict__ zrdy,
        float* __restrict__ out) {
    __shared__ __align__(16) char ldsraw[LDS_BYTES];
    const int tid = threadIdx.x;
    const int bid = blockIdx.x;

    const int wave = tid >> 6;
    const int lane = tid & 63;
    const int fr   = lane & 15;
    const int quad = lane >> 4;

    if (bid >= 256) {
        // ================= zgemm role (R10-proven body) =================
        _Float16* la = reinterpret_cast<_Float16*>(ldsraw);
        _Float16* lb = la + 128 * LGW;

        const int id   = bid - 256;                // 0..4095
        const int nblk = (id >> 3) & 7;            // 0..7
        const int mblk = (id & 7) + 8 * (id >> 6); // 0..511
        const int m0 = mblk * 128;
        const int n0 = nblk * 128;

        const float* __restrict__ X = seq + (size_t)m0 * 1024;
        float* __restrict__ Z = out + (size_t)BATCH * DH + (size_t)m0 * 1024 + n0;

        const int ar = tid >> 1;
        const int kh = tid & 1;
        const float*    Asrc = X  + (size_t)ar * 1024 + kh * 32;
        const _Float16* Bsrc = Wx + (size_t)(n0 + ar) * 1024 + kh * 32;

        float4 af[8];
        uint4  bq[4];
        auto load_tiles = [&](int kb) {
            const float4* s4 = reinterpret_cast<const float4*>(Asrc + kb);
#pragma unroll
            for (int i = 0; i < 8; ++i) af[i] = s4[i];
            const uint4* sb = reinterpret_cast<const uint4*>(Bsrc + kb);
#pragma unroll
            for (int i = 0; i < 4; ++i) bq[i] = sb[i];
        };
        auto store_tiles = [&]() {
#pragma unroll
            for (int j = 0; j < 4; ++j) {
                half8_t h;
                h[0] = (_Float16)af[2 * j].x;     h[1] = (_Float16)af[2 * j].y;
                h[2] = (_Float16)af[2 * j].z;     h[3] = (_Float16)af[2 * j].w;
                h[4] = (_Float16)af[2 * j + 1].x; h[5] = (_Float16)af[2 * j + 1].y;
                h[6] = (_Float16)af[2 * j + 1].z; h[7] = (_Float16)af[2 * j + 1].w;
                *reinterpret_cast<half8_t*>(&la[ar * LGW + kh * 32 + j * 8]) = h;
            }
#pragma unroll
            for (int i = 0; i < 4; ++i)
                *reinterpret_cast<uint4*>(&lb[ar * LGW + kh * 32 + i * 8]) = bq[i];
        };

        const int wm = (wave >> 1) * 64;
        const int wn = (wave & 1) * 64;

        f32x4_t acc[4][4];
#pragma unroll
        for (int i = 0; i < 4; ++i)
#pragma unroll
            for (int j = 0; j < 4; ++j) acc[i][j] = (f32x4_t){0.f, 0.f, 0.f, 0.f};

        load_tiles(0);
#pragma unroll 1
        for (int it = 0; it < 16; ++it) {
            store_tiles();
            __syncthreads();
            if (it < 15) load_tiles((it + 1) * 64);
#pragma unroll
            for (int kk = 0; kk < 2; ++kk) {
                const int ko = kk * 32 + quad * 8;
                half8_t a[4], b[4];
#pragma unroll
                for (int mi = 0; mi < 4; ++mi)
                    a[mi] = *reinterpret_cast<const half8_t*>(
                        &la[(wm + mi * 16 + fr) * LGW + ko]);
#pragma unroll
                for (int ni = 0; ni < 4; ++ni)
                    b[ni] = *reinterpret_cast<const half8_t*>(
                        &lb[(wn + ni * 16 + fr) * LGW + ko]);
#pragma unroll
                for (int mi = 0; mi < 4; ++mi)
#pragma unroll
                    for (int ni = 0; ni < 4; ++ni)
                        acc[mi][ni] = __builtin_amdgcn_mfma_f32_16x16x32_f16(
                            a[mi], b[ni], acc[mi][ni], 0, 0, 0);
            }
            __syncthreads();
        }

        // Epilogue: bias + SYSTEM write-through stores (IF$ authoritative).
#pragma unroll
        for (int ni = 0; ni < 4; ++ni) {
            const float bv = bias[n0 + wn + ni * 16 + fr];
#pragma unroll
            for (int mi = 0; mi < 4; ++mi) {
                const int mr = wm + mi * 16 + quad * 4;
#pragma unroll
                for (int q = 0; q < 4; ++q)
                    __hip_atomic_store(
                        &Z[(size_t)(mr + q) * 1024 + wn + ni * 16 + fr],
                        acc[mi][ni][q] + bv,
                        __ATOMIC_RELAXED, __HIP_MEMORY_SCOPE_SYSTEM);
            }
        }
        __syncthreads();   // all threads' write-through stores drained
        if (tid == 0)
            __hip_atomic_store(&zrdy[mblk * 8 + nblk], 1,
                               __ATOMIC_RELAXED, __HIP_MEMORY_SCOPE_SYSTEM);
        return;
    }

    // ================= rnn role (R4/R10-proven protocol) =================
    _Float16* hL   = reinterpret_cast<_Float16*>(ldsraw);
    float*    redL = reinterpret_cast<float*>(ldsraw + 16 * LDH * 2);

    const int m = bid & 15;
    const int n = bid >> 4;

    // Wh fragments: wave's 16 cols x K=1024 -> 32 x half8 = 128 VGPRs.
    half8_t bfrag[32];
    {
        const _Float16* wp = Wh + (size_t)(n * 64 + wave * 16 + fr) * DH + quad * 8;
#pragma unroll
        for (int ks = 0; ks < 32; ++ks)
            bfrag[ks] = *reinterpret_cast<const half8_t*>(wp + ks * 32);
    }

    const int r  = tid >> 4;          // 0..15 batch row within tile
    const int c4 = (tid & 15) * 4;    // 0..60 col within tile
    const size_t orowg = (size_t)(m * 16 + r);
    int* myflag = flags + (m * 16 + n) * 16;
    const int zcol = n >> 1;          // zgemm nblk covering cols n*64..n*64+64
    const int mhalf = m >> 3;         // 0 (rows<128) or 1

    // ---- t = 0: h1 = tanh(Z_0) since h0 == 0 ----
    {
        if (tid == 0) {
            const int* zf = zrdy + (0 + mhalf) * 8 + zcol;
            int g = 0;
            while (!__hip_atomic_load(zf, __ATOMIC_RELAXED,
                                      __HIP_MEMORY_SCOPE_SYSTEM)) {
                if (++g > (1 << 25)) break;
            }
        }
        __syncthreads();

        float* o1 = out + ((size_t)BATCH + orowg) * DH + n * 64 + c4;
        float zv[4];
#pragma unroll
        for (int j = 0; j < 4; ++j)
            zv[j] = __hip_atomic_load(o1 + j, __ATOMIC_RELAXED,
                                      __HIP_MEMORY_SCOPE_SYSTEM);
        float4 v = make_float4(ftanh(zv[0]), ftanh(zv[1]),
                               ftanh(zv[2]), ftanh(zv[3]));
        *reinterpret_cast<float4*>(o1) = v;
        H4U cv;
        cv.h[0] = (_Float16)v.x; cv.h[1] = (_Float16)v.y;
        cv.h[2] = (_Float16)v.z; cv.h[3] = (_Float16)v.w;
        __hip_atomic_store(
            (unsigned long long*)(Hh + ((size_t)BATCH + orowg) * DH + n * 64 + c4),
            cv.u, __ATOMIC_RELAXED, __HIP_MEMORY_SCOPE_SYSTEM);
        __syncthreads();   // all write-through stores vmcnt-drained
        if (tid == 0)
            __hip_atomic_store(myflag, 1, __ATOMIC_RELAXED, __HIP_MEMORY_SCOPE_SYSTEM);
    }

    for (int s = 1; s < T_STEPS; ++s) {
        // Wait for the 16 h-producers of group m (step s) AND this WG's
        // Z tile (2s + mhalf, zcol) from the zgemm role.
        if (tid < 16) {
            const int* f = flags + (m * 16 + tid) * 16;
            int guard = 0;
            while (__hip_atomic_load(f, __ATOMIC_RELAXED,
                                     __HIP_MEMORY_SCOPE_SYSTEM) < s) {
                if (++guard > (1 << 25)) break;
            }
        } else if (tid == 16) {
            const int* zf = zrdy + (2 * s + mhalf) * 8 + zcol;
            int guard = 0;
            while (!__hip_atomic_load(zf, __ATOMIC_RELAXED,
                                      __HIP_MEMORY_SCOPE_SYSTEM)) {
                if (++guard > (1 << 25)) break;
            }
        }
        __syncthreads();

        // Stage h_s slab (16 x 1024 fp16 = 32 KB) into LDS, bypassing L1/L2.
        const _Float16* hsrc = Hh + ((size_t)(s & 1) * BATCH + (size_t)m * 16) * DH;
#pragma unroll
        for (int i = 0; i < 8; ++i) {
            const int c   = wave * 8 + i;    // 0..31 chunks of 1 KB
            const int row = c >> 1;
            const int hf  = c & 1;
            const _Float16* src = hsrc + (size_t)row * DH + hf * 512 + lane * 8;
            __builtin_amdgcn_global_load_lds(
                (const __attribute__((address_space(1))) void*)src,
                (__attribute__((address_space(3))) void*)&hL[row * LDH + hf * 512],
                16, 0, CPOL_SYS);
        }
        // Z loads (system-bypass; producer wrote write-through). Latency
        // overlaps the h-slab staging above.
        float* o = out + ((size_t)(s + 1) * BATCH + orowg) * DH + n * 64 + c4;
        float zv[4];
#pragma unroll
        for (int j = 0; j < 4; ++j)
            zv[j] = __hip_atomic_load(o + j, __ATOMIC_RELAXED,
                                      __HIP_MEMORY_SCOPE_SYSTEM);
        __syncthreads();

        // 32 MFMAs, two interleaved accumulator chains.
        f32x4_t acc0 = {0.f, 0.f, 0.f, 0.f}, acc1 = {0.f, 0.f, 0.f, 0.f};
        const _Float16* pa = &hL[fr * LDH + quad * 8];
#pragma unroll
        for (int ks = 0; ks < 16; ++ks) {
            half8_t ae = *reinterpret_cast<const half8_t*>(pa + (2 * ks) * 32);
            half8_t ao = *reinterpret_cast<const half8_t*>(pa + (2 * ks + 1) * 32);
            acc0 = __builtin_amdgcn_mfma_f32_16x16x32_f16(ae, bfrag[2 * ks],     acc0, 0, 0, 0);
            acc1 = __builtin_amdgcn_mfma_f32_16x16x32_f16(ao, bfrag[2 * ks + 1], acc1, 0, 0, 0);
        }
        f32x4_t sum = acc0 + acc1;

        // Transpose D-layout (row=quad*4+q batch, col=wave*16+fr) via LDS.
#pragma unroll
        for (int q = 0; q < 4; ++q)
            redL[(quad * 4 + q) * REDW + wave * 16 + fr] = sum[q];
        __syncthreads();

        f32x4_t t4 = *reinterpret_cast<const f32x4_t*>(&redL[r * REDW + c4]);
        float4 v = make_float4(ftanh(t4[0] + zv[0]), ftanh(t4[1] + zv[1]),
                               ftanh(t4[2] + zv[2]), ftanh(t4[3] + zv[3]));
        *reinterpret_cast<float4*>(o) = v;
        H4U cv;
        cv.h[0] = (_Float16)v.x; cv.h[1] = (_Float16)v.y;
        cv.h[2] = (_Float16)v.z; cv.h[3] = (_Float16)v.w;
        __hip_atomic_store(
            (unsigned long long*)(Hh + ((size_t)((s + 1) & 1) * BATCH + orowg) * DH
                                  + n * 64 + c4),
            cv.u, __ATOMIC_RELAXED, __HIP_MEMORY_SCOPE_SYSTEM);

        __syncthreads();   // every thread's write-through stores drained
        if (tid == 0)
            __hip_atomic_store(myflag, s + 1, __ATOMIC_RELAXED, __HIP_MEMORY_SCOPE_SYSTEM);
    }
}

// ---------------------------------------------------------------------------
// Workspace layout (bytes):
//   [0, 2M)       Wh fp16 (1024 x 1024)
//   [2M, 4M)      Wx fp16 (1024 x 1024)
//   [4M, 5M)      Hh fp16 double buffer (2 x 256 x 1024)
//   [5M, 5M+16K)  flags int[256][16]
//   [5M+16K, +16K) zrdy int[512][8]
// ---------------------------------------------------------------------------
extern "C" void kernel_launch(void* const* d_in, const int* in_sizes, int n_in,
                              void* d_out, int out_size, void* d_ws, size_t ws_size,
                              hipStream_t stream) {
    const float* seq  = (const float*)d_in[0];   // (256, 256, 1024) fp32
    const float* W    = (const float*)d_in[1];   // (1024, 2048) fp32
    const float* bias = (const float*)d_in[2];   // (1024,) fp32
    float* out        = (float*)d_out;           // (257, 256, 1024) fp32
    _Float16* Wh      = (_Float16*)d_ws;
    _Float16* Wx      = (_Float16*)d_ws + 1024 * 1024;
    _Float16* Hh      = (_Float16*)d_ws + 2 * 1024 * 1024;
    int* flags        = (int*)((char*)d_ws + 5 * 1024 * 1024);
    int* zrdy         = (int*)((char*)d_ws + 5 * 1024 * 1024 + 16 * 1024);

    hipLaunchKernelGGL(cvt_w, dim3(1024), dim3(256), 0, stream, W, Wh, Wx);
    hipLaunchKernelGGL(zero_h0, dim3(256), dim3(256), 0, stream, out, flags, zrdy);
    hipLaunchKernelGGL(fused_pipeline, dim3(256 + 4096), dim3(256), 0, stream,
                       Wh, Wx, bias, seq, Hh, flags, zrdy, out);
}